// Round 8
// baseline (160.173 us; speedup 1.0000x reference)
//
#include <hip/hip_runtime.h>
#include <hip/hip_bf16.h>
#include <math.h>

#define B_    32
#define L_    4096
#define UNITS 512
#define ROWS  (B_ * L_)          // 131072
#define PI_F  3.14159265358979323846f
#define HLOG2E 0.7213475204444817f   // 0.5*log2(e)
#define LOG2E  1.4426950408889634f
#define TLOG2E 2.8853900817779268f   // 2*log2(e)

typedef __attribute__((ext_vector_type(8))) short short8;
typedef __attribute__((ext_vector_type(4))) float f32x4;

__device__ inline float fexp2(float x) { return __builtin_amdgcn_exp2f(x); }
__device__ inline float frcp(float x)  { return __builtin_amdgcn_rcpf(x); }
__device__ inline float fsin1(float r) { return __builtin_amdgcn_sinf(r); }  // sin(2*pi*r)
__device__ inline float fcos1(float r) { return __builtin_amdgcn_cosf(r); }  // cos(2*pi*r)
__device__ inline float ftanh(float y) {
    float e = fexp2(y * TLOG2E);               // e^(2y)
    return 1.0f - 2.0f * frcp(e + 1.0f);
}

__device__ inline ushort f2bf(float f) {
    uint u = __float_as_uint(f);
    return (ushort)((u + 0x7fffu + ((u >> 16) & 1u)) >> 16);   // RNE
}
__device__ inline float bf2f(ushort h) { return __uint_as_float(((uint)h) << 16); }

// split two f32 into packed bf16 hi + packed bf16 lo (RNE both)
__device__ inline void split2(float f0, float f1, uint& hi, uint& lo) {
    __hip_bfloat162 h2 = __float22bfloat162_rn(make_float2(f0, f1));
    hi = *reinterpret_cast<uint*>(&h2);
    float h0 = __uint_as_float(hi << 16);
    float h1 = __uint_as_float(hi & 0xffff0000u);
    __hip_bfloat162 l2 = __float22bfloat162_rn(make_float2(f0 - h0, f1 - h1));
    lo = *reinterpret_cast<uint*>(&l2);
}

__device__ inline void onl(float& m, float& s, float m2, float s2) {
    float nm = fmaxf(m, m2);
    s = s * fexp2((m - nm) * LOG2E) + s2 * fexp2((m2 - nm) * LOG2E);
    m = nm;
}

// ---------------- workspace layout (bytes), total ~1.3 MB ----------------
#define OFF_WHT   ((size_t)0)                    // [128][512] bf16 hi (W^T, permuted cols)
#define OFF_WLT   (OFF_WHT + (size_t)131072)     // [128][512] bf16 lo
#define OFF_PSW   (OFF_WLT + (size_t)131072)     // [512] float2 psi weights
#define OFF_PRI   (OFF_PSW + (size_t)4096)       // [1024][64] float2 partial re/im
#define OFF_PMPHI (OFF_PRI + (size_t)524288)     // [1024][64] f32
#define OFF_PSPHI (OFF_PMPHI + (size_t)262144)
#define OFF_PMPSI (OFF_PSPHI + (size_t)262144)   // [1024]
#define OFF_PSPSI (OFF_PMPSI + (size_t)4096)

// K0 (verbatim R5): split weights into bf16 hi/lo, W^T [128][512] with column
// permutation pr=((n>>5)<<6)|(n&31) for phi_r col n, pr+32 for phi_theta.
__global__ void k0_pack(const float* __restrict__ psi_r, const float* __restrict__ psi_t,
                        const float* __restrict__ phi_r, const float* __restrict__ phi_t,
                        ushort* __restrict__ wht, ushort* __restrict__ wlt,
                        float2* __restrict__ psw) {
    const int k = blockIdx.x;     // 0..511
    const int n = threadIdx.x;    // 0..63
    const int pr = ((n >> 5) << 6) | (n & 31);
    const int pt = pr + 32;
    float w0 = phi_r[k * 64 + n];
    float w1 = phi_t[k * 64 + n];
    ushort h0 = f2bf(w0), h1 = f2bf(w1);
    wht[(size_t)pr * 512 + k] = h0;
    wht[(size_t)pt * 512 + k] = h1;
    wlt[(size_t)pr * 512 + k] = f2bf(w0 - bf2f(h0));
    wlt[(size_t)pt * 512 + k] = f2bf(w1 - bf2f(h1));
    if (n == 0) psw[k] = make_float2(psi_r[k], psi_t[k]);
}

// K1: z = x @ W via 3-pass split-bf16 MFMA, BARRIER-FREE main loop:
//  - A fragments: two aligned dwordx4 per (mi,iter) straight from x (the MFMA
//    A-layout is row-major like x). wc-pair redundancy served by L1/L2.
//  - B fragments: direct from L2-resident wht/wlt (R6-verified addressing).
//  - psi: fmaf on the same fp32 A fragments vs a pswl slice (R7-verified
//    ordering), shfl-reduced across hi16 groups in the epilogue.
//  No LDS ops, no __syncthreads, no sched_barrier in the loop -> compiler
//  schedules vmcnt progressively; independent waves provide the latency hiding.
// Fused epilogue identical to R7 (passed): psi amplitude-phase, zuv staging,
// explicit (row,state) reduction, softmax partials.
__global__ __launch_bounds__(256) void k1_gemm(
        const float* __restrict__ x,
        const uint4* __restrict__ wht4, const uint4* __restrict__ wlt4,
        const float2* __restrict__ psw_g,
        const float* __restrict__ psi_tb_p, const float* __restrict__ phi_tb_p,
        float2* __restrict__ pri,
        float* __restrict__ pmphi, float* __restrict__ psphi,
        float* __restrict__ pmpsi, float* __restrict__ pspsi) {
    __shared__ __align__(16) uint smem[9600];       // 38400 B: epilogue zuv/stats
    float2* const zuv = (float2*)smem;              // [128][33] float2 = 33792 B
    float* const als    = (float*)(smem + 8448);
    float* const bls    = (float*)(smem + 8576);
    float* const psr    = (float*)(smem + 8704);
    float* const stat_m = (float*)(smem + 8832);    // [4][32] flat
    float* const stat_s = (float*)(smem + 8960);
    float2* const red   = (float2*)(smem + 9088);   // [8][32] flat
    __shared__ __align__(16) float2 pswl[512];      // 4096 B

    const int t    = threadIdx.x;
    const int lane = t & 63;
    const int w = t >> 6, wr = w >> 1, wc = w & 1;
    const int r0 = blockIdx.x * 128;
    const int hi16 = lane >> 4, lo16 = lane & 15;

    ((float4*)pswl)[t] = ((const float4*)psw_g)[t];     // 4 KB

    f32x4 acc[4][4];
    #pragma unroll
    for (int i = 0; i < 4; ++i)
        #pragma unroll
        for (int j = 0; j < 4; ++j) acc[i][j] = (f32x4)0.f;
    float paccr[4] = {0.f, 0.f, 0.f, 0.f}, pacct[4] = {0.f, 0.f, 0.f, 0.f};

    // per-lane A base: row = wr*64 + mi*16 + lo16, col = kt + hi16*8
    const float* xl = x + (size_t)(r0 + (wr << 6) + lo16) * 512 + (hi16 << 3);

    __syncthreads();   // pswl visible (only barrier before epilogue)

    for (int kt = 0; kt < 512; kt += 32) {
        // ---- issue all global loads for this k-tile ----
        f32x4 va[4][2];
        #pragma unroll
        for (int mi = 0; mi < 4; ++mi) {
            const float* rp = xl + (size_t)(mi << 4) * 512 + kt;
            va[mi][0] = *(const f32x4*)rp;
            va[mi][1] = *(const f32x4*)(rp + 4);
        }
        uint4 vbh[4], vbl[4];
        #pragma unroll
        for (int nj = 0; nj < 4; ++nj) {
            const int row = (wc << 6) + (nj << 4) + lo16;       // packed W^T row
            const size_t gi = (size_t)row * 64 + (kt >> 3) + hi16;  // uint4 units
            vbh[nj] = wht4[gi];
            vbl[nj] = wlt4[gi];
        }
        // ---- psw slice for this lane's k-range (broadcast LDS reads) ----
        float4 pw[4];
        #pragma unroll
        for (int c = 0; c < 4; ++c)
            pw[c] = ((const float4*)pswl)[((kt + (hi16 << 3)) >> 1) + c];

        // ---- psi fmaf + split to bf16 ----
        short8 ahf[4], alf[4];
        #pragma unroll
        for (int mi = 0; mi < 4; ++mi) {
            f32x4 v0 = va[mi][0], v1 = va[mi][1];
            paccr[mi] = fmaf(v0[0], pw[0].x, paccr[mi]); pacct[mi] = fmaf(v0[0], pw[0].y, pacct[mi]);
            paccr[mi] = fmaf(v0[1], pw[0].z, paccr[mi]); pacct[mi] = fmaf(v0[1], pw[0].w, pacct[mi]);
            paccr[mi] = fmaf(v0[2], pw[1].x, paccr[mi]); pacct[mi] = fmaf(v0[2], pw[1].y, pacct[mi]);
            paccr[mi] = fmaf(v0[3], pw[1].z, paccr[mi]); pacct[mi] = fmaf(v0[3], pw[1].w, pacct[mi]);
            paccr[mi] = fmaf(v1[0], pw[2].x, paccr[mi]); pacct[mi] = fmaf(v1[0], pw[2].y, pacct[mi]);
            paccr[mi] = fmaf(v1[1], pw[2].z, paccr[mi]); pacct[mi] = fmaf(v1[1], pw[2].w, pacct[mi]);
            paccr[mi] = fmaf(v1[2], pw[3].x, paccr[mi]); pacct[mi] = fmaf(v1[2], pw[3].y, pacct[mi]);
            paccr[mi] = fmaf(v1[3], pw[3].z, paccr[mi]); pacct[mi] = fmaf(v1[3], pw[3].w, pacct[mi]);
            uint h0, l0, h1, l1, h2, l2, h3, l3;
            split2(v0[0], v0[1], h0, l0);
            split2(v0[2], v0[3], h1, l1);
            split2(v1[0], v1[1], h2, l2);
            split2(v1[2], v1[3], h3, l3);
            uint4 ah = make_uint4(h0, h1, h2, h3), al = make_uint4(l0, l1, l2, l3);
            ahf[mi] = *reinterpret_cast<short8*>(&ah);
            alf[mi] = *reinterpret_cast<short8*>(&al);
        }
        short8 bhf[4], blf[4];
        #pragma unroll
        for (int nj = 0; nj < 4; ++nj) {
            bhf[nj] = *reinterpret_cast<short8*>(&vbh[nj]);
            blf[nj] = *reinterpret_cast<short8*>(&vbl[nj]);
        }

        // ---- MFMA phase (regs only) ----
        #pragma unroll
        for (int nj = 0; nj < 4; ++nj) {
            #pragma unroll
            for (int mi = 0; mi < 4; ++mi) {
                acc[mi][nj] = __builtin_amdgcn_mfma_f32_16x16x32_bf16(ahf[mi], bhf[nj], acc[mi][nj], 0, 0, 0);
                acc[mi][nj] = __builtin_amdgcn_mfma_f32_16x16x32_bf16(ahf[mi], blf[nj], acc[mi][nj], 0, 0, 0);
                acc[mi][nj] = __builtin_amdgcn_mfma_f32_16x16x32_bf16(alf[mi], bhf[nj], acc[mi][nj], 0, 0, 0);
            }
        }
    }

    // ================= epilogue (verbatim R7, passed) =================
    // part 1: psi — reduce per-lane partials across hi16 groups; trans per row
    #pragma unroll
    for (int mi = 0; mi < 4; ++mi) {
        paccr[mi] += __shfl_xor(paccr[mi], 16);
        paccr[mi] += __shfl_xor(paccr[mi], 32);
        pacct[mi] += __shfl_xor(pacct[mi], 16);
        pacct[mi] += __shfl_xor(pacct[mi], 32);
    }
    if (wc == 0 && lane < 16) {
        const float psi_tb = psi_tb_p[0];
        #pragma unroll
        for (int mi = 0; mi < 4; ++mi) {
            const int row = (wr << 6) + (mi << 4) + lane;
            float zr = paccr[mi], zt = pacct[mi];
            float e = fexp2(zr * HLOG2E);
            float tt = ftanh(zt + psi_tb);
            float rev = (1.0f + tt) * 0.5f;
            als[row] = e * fcos1(rev);
            bls[row] = e * fsin1(rev);
            psr[row] = zr;
        }
    }
    __syncthreads();

    // part 2: two passes over nj; stage (u,v) in zuv, reduce with explicit
    // (row,state) indexing.
    const float phi_tb = phi_tb_p[0];
    #pragma unroll
    for (int nj = 0; nj < 2; ++nj) {
        float m = -3.4e38f, s = 0.f;
        #pragma unroll
        for (int mi = 0; mi < 4; ++mi) {
            const int rl = wr * 64 + mi * 16 + hi16 * 4;
            #pragma unroll
            for (int r = 0; r < 4; ++r) {
                float zr = acc[mi][nj][r];
                float zt = acc[mi][nj + 2][r];
                float eh = fexp2(zr * HLOG2E);
                float tt = ftanh(zt + phi_tb);
                float rev = -(1.0f + PI_F * tt) * 0.5f;
                rev = rev - floorf(rev);
                float u = eh * fcos1(rev), v = eh * fsin1(rev);
                zuv[(rl + r) * 33 + wc * 16 + lo16] = make_float2(u, v);
                float nm = fmaxf(m, zr);
                s = s * fexp2((m - nm) * LOG2E) + fexp2((zr - nm) * LOG2E);
                m = nm;
            }
        }
        #pragma unroll
        for (int off = 16; off <= 32; off <<= 1) {
            float m2 = __shfl_xor(m, off);
            float s2 = __shfl_xor(s, off);
            onl(m, s, m2, s2);
        }
        if (lane < 16) { stat_m[w * 32 + nj * 16 + lo16] = m; stat_s[w * 32 + nj * 16 + lo16] = s; }
        __syncthreads();

        {
            const int slot = t & 31, q = t >> 5;
            float re = 0.f, im = 0.f;
            #pragma unroll
            for (int i = 0; i < 16; ++i) {
                const int row = q + 8 * i;
                float2 uvv = zuv[row * 33 + slot];
                float a = als[row], b2 = bls[row];
                re = fmaf(a, uvv.x, fmaf(b2, uvv.y, re));   // cos(A-B)
                im = fmaf(b2, uvv.x, fmaf(-a, uvv.y, im));  // sin(A-B)
            }
            red[q * 32 + slot] = make_float2(re, im);
        }
        __syncthreads();
        if (t < 32) {
            float re = 0.f, im = 0.f;
            #pragma unroll
            for (int q = 0; q < 8; ++q) { re += red[q * 32 + t].x; im += red[q * 32 + t].y; }
            const int state = ((t >> 4) << 5) | (nj << 4) | (t & 15);
            pri[(size_t)blockIdx.x * 64 + state] = make_float2(re, im);
        }
        __syncthreads();
    }

    // part 3: combine per-wave stats -> per-block partials
    if (t < 64) {
        const int wcn = t >> 5, nloc = t & 31;
        float M = stat_m[wcn * 32 + nloc], S = stat_s[wcn * 32 + nloc];
        onl(M, S, stat_m[(wcn + 2) * 32 + nloc], stat_s[(wcn + 2) * 32 + nloc]);
        pmphi[(size_t)blockIdx.x * 64 + t] = M;
        psphi[(size_t)blockIdx.x * 64 + t] = S;
    } else if (t < 128) {
        const int i = t - 64;
        float a = psr[i], bb = psr[i + 64];
        float M = fmaxf(a, bb);
        float S = fexp2((a - M) * LOG2E) + fexp2((bb - M) * LOG2E);
        #pragma unroll
        for (int off = 1; off <= 32; off <<= 1) {
            float m2 = __shfl_xor(M, off);
            float s2 = __shfl_xor(S, off);
            onl(M, S, m2, s2);
        }
        if (i == 0) { pmpsi[blockIdx.x] = M; pspsi[blockIdx.x] = S; }
    }
}

// K5: per batch: combine 32 block partials -> scales -> collapse -> out GEMM
__global__ __launch_bounds__(512) void k5_out(
        const float2* __restrict__ pri,
        const float* __restrict__ pmphi, const float* __restrict__ psphi,
        const float* __restrict__ pmpsi, const float* __restrict__ pspsi,
        const float* __restrict__ Smat, const float* __restrict__ sb_p,
        float* __restrict__ out) {
    const int b = blockIdx.x, t = threadIdx.x;
    __shared__ float cls[64];
    __shared__ float spsi_s;
    float sph = 0.f, re = 0.f, im = 0.f;
    if (t < 64) {
        float M = -3.4e38f, S = 0.f;
        for (int ch = 0; ch < 32; ++ch)
            onl(M, S, pmphi[(size_t)(b * 32 + ch) * 64 + t], psphi[(size_t)(b * 32 + ch) * 64 + t]);
        sph = fexp2(-M * HLOG2E) / sqrtf(S);
        for (int ch = 0; ch < 32; ++ch) {
            float2 p = pri[(size_t)(b * 32 + ch) * 64 + t];
            re += p.x; im += p.y;
        }
    } else if (t == 64) {
        float M = -3.4e38f, S = 0.f;
        for (int ch = 0; ch < 32; ++ch)
            onl(M, S, pmpsi[b * 32 + ch], pspsi[b * 32 + ch]);
        spsi_s = fexp2(-M * HLOG2E) / sqrtf(S);
    }
    __syncthreads();
    if (t < 64) {
        float sc = spsi_s * sph;
        cls[t] = sc * sc * (re * re + im * im);
    }
    __syncthreads();
    float acc = sb_p[0];
    #pragma unroll 8
    for (int n = 0; n < 64; ++n) acc = fmaf(cls[n], Smat[n * UNITS + t], acc);
    out[(size_t)b * UNITS + t] = acc;
}

extern "C" void kernel_launch(void* const* d_in, const int* in_sizes, int n_in,
                              void* d_out, int out_size, void* d_ws, size_t ws_size,
                              hipStream_t stream) {
    const float* x      = (const float*)d_in[0];
    const float* psi_r  = (const float*)d_in[1];
    const float* psi_t  = (const float*)d_in[2];
    const float* psi_tb = (const float*)d_in[3];
    const float* phi_r  = (const float*)d_in[4];
    const float* phi_t  = (const float*)d_in[5];
    const float* phi_tb = (const float*)d_in[6];
    const float* Smat   = (const float*)d_in[7];
    const float* sb     = (const float*)d_in[8];
    float* out = (float*)d_out;

    char* ws = (char*)d_ws;
    ushort* wht  = (ushort*)(ws + OFF_WHT);
    ushort* wlt  = (ushort*)(ws + OFF_WLT);
    float2* psw  = (float2*)(ws + OFF_PSW);
    float2* pri  = (float2*)(ws + OFF_PRI);
    float* pmphi = (float*)(ws + OFF_PMPHI);
    float* psphi = (float*)(ws + OFF_PSPHI);
    float* pmpsi = (float*)(ws + OFF_PMPSI);
    float* pspsi = (float*)(ws + OFF_PSPSI);

    k0_pack<<<512, 64, 0, stream>>>(psi_r, psi_t, phi_r, phi_t, wht, wlt, psw);
    k1_gemm<<<ROWS / 128, 256, 0, stream>>>(x, (const uint4*)wht, (const uint4*)wlt, psw,
                                            psi_tb, phi_tb, pri, pmphi, psphi, pmpsi, pspsi);
    k5_out<<<B_, 512, 0, stream>>>(pri, pmphi, psphi, pmpsi, pspsi, Smat, sb, out);
}

// Round 9
// 110.618 us; speedup vs baseline: 1.4480x; 1.4480x over previous
//
#include <hip/hip_runtime.h>
#include <hip/hip_bf16.h>
#include <math.h>

#define B_    32
#define L_    4096
#define UNITS 512
#define ROWS  (B_ * L_)          // 131072
#define PI_F  3.14159265358979323846f
#define HLOG2E 0.7213475204444817f   // 0.5*log2(e)
#define LOG2E  1.4426950408889634f
#define TLOG2E 2.8853900817779268f   // 2*log2(e)

typedef __attribute__((ext_vector_type(8))) short short8;
typedef __attribute__((ext_vector_type(4))) float f32x4;

__device__ inline float fexp2(float x) { return __builtin_amdgcn_exp2f(x); }
__device__ inline float frcp(float x)  { return __builtin_amdgcn_rcpf(x); }
__device__ inline float fsin1(float r) { return __builtin_amdgcn_sinf(r); }  // sin(2*pi*r)
__device__ inline float fcos1(float r) { return __builtin_amdgcn_cosf(r); }  // cos(2*pi*r)
__device__ inline float ftanh(float y) {
    float e = fexp2(y * TLOG2E);               // e^(2y)
    return 1.0f - 2.0f * frcp(e + 1.0f);
}

__device__ inline ushort f2bf(float f) {
    uint u = __float_as_uint(f);
    return (ushort)((u + 0x7fffu + ((u >> 16) & 1u)) >> 16);   // RNE
}
__device__ inline float bf2f(ushort h) { return __uint_as_float(((uint)h) << 16); }

// split two f32 into packed bf16 hi + packed bf16 lo (RNE both)
__device__ inline void split2(float f0, float f1, uint& hi, uint& lo) {
    __hip_bfloat162 h2 = __float22bfloat162_rn(make_float2(f0, f1));
    hi = *reinterpret_cast<uint*>(&h2);
    float h0 = __uint_as_float(hi << 16);
    float h1 = __uint_as_float(hi & 0xffff0000u);
    __hip_bfloat162 l2 = __float22bfloat162_rn(make_float2(f0 - h0, f1 - h1));
    lo = *reinterpret_cast<uint*>(&l2);
}

__device__ inline void onl(float& m, float& s, float m2, float s2) {
    float nm = fmaxf(m, m2);
    s = s * fexp2((m - nm) * LOG2E) + s2 * fexp2((m2 - nm) * LOG2E);
    m = nm;
}

// async global->LDS, 16B per lane; lds dst is wave-uniform base (HW adds lane*16)
__device__ inline void gload16(const void* g, uint* l) {
    __builtin_amdgcn_global_load_lds((const __attribute__((address_space(1))) uint*)g,
                                     (__attribute__((address_space(3))) uint*)l, 16, 0, 0);
}

// ---------------- workspace layout (bytes), total ~1.3 MB ----------------
#define OFF_WHT   ((size_t)0)                    // [128][512] bf16 hi (W^T, permuted cols)
#define OFF_WLT   (OFF_WHT + (size_t)131072)     // [128][512] bf16 lo
#define OFF_PSW   (OFF_WLT + (size_t)131072)     // [512] float2 psi weights
#define OFF_PRI   (OFF_PSW + (size_t)4096)       // [1024][64] float2 partial re/im
#define OFF_PMPHI (OFF_PRI + (size_t)524288)     // [1024][64] f32
#define OFF_PSPHI (OFF_PMPHI + (size_t)262144)
#define OFF_PMPSI (OFF_PSPHI + (size_t)262144)   // [1024]
#define OFF_PSPSI (OFF_PMPSI + (size_t)4096)

// K0 (verbatim R5): split weights into bf16 hi/lo, W^T [128][512] with column
// permutation pr=((n>>5)<<6)|(n&31) for phi_r col n, pr+32 for phi_theta.
__global__ void k0_pack(const float* __restrict__ psi_r, const float* __restrict__ psi_t,
                        const float* __restrict__ phi_r, const float* __restrict__ phi_t,
                        ushort* __restrict__ wht, ushort* __restrict__ wlt,
                        float2* __restrict__ psw) {
    const int k = blockIdx.x;     // 0..511
    const int n = threadIdx.x;    // 0..63
    const int pr = ((n >> 5) << 6) | (n & 31);
    const int pt = pr + 32;
    float w0 = phi_r[k * 64 + n];
    float w1 = phi_t[k * 64 + n];
    ushort h0 = f2bf(w0), h1 = f2bf(w1);
    wht[(size_t)pr * 512 + k] = h0;
    wht[(size_t)pt * 512 + k] = h1;
    wlt[(size_t)pr * 512 + k] = f2bf(w0 - bf2f(h0));
    wlt[(size_t)pt * 512 + k] = f2bf(w1 - bf2f(h1));
    if (n == 0) psw[k] = make_float2(psi_r[k], psi_t[k]);
}

// K1: z = x @ W via 3-pass split-bf16 MFMA, m97-style staging:
//  - A: raw fp32 x DMA'd via global_load_lds into a 2x16KB double buffer.
//    Linear LDS dst; source col-group pre-swizzled g^(row&7) and fragment
//    read XOR-swizzled (R7-verified addressing) -> <=2-way bank conflicts.
//    bf16 hi/lo split AFTER the LDS read (bit-identical MFMA inputs).
//  - B: fragments direct from L2-resident wht/wlt (R6-verified addressing).
//  - psi: fmaf on the fp32 A fragments vs pswl slice (R8-verified ordering),
//    computed by wc==0 waves only.
//  ONE __syncthreads per k-iter; no inline asm, no sched_barrier — the
//  compiler's vmcnt(0) drain at the barrier completes the next tile's DMA,
//  which had the whole MFMA phase to fly.
__global__ __launch_bounds__(256) void k1_gemm(
        const float* __restrict__ x,
        const uint4* __restrict__ wht4, const uint4* __restrict__ wlt4,
        const float2* __restrict__ psw_g,
        const float* __restrict__ psi_tb_p, const float* __restrict__ phi_tb_p,
        float2* __restrict__ pri,
        float* __restrict__ pmphi, float* __restrict__ psphi,
        float* __restrict__ pmpsi, float* __restrict__ pspsi) {
    __shared__ __align__(16) uint smem[9600];       // 38400 B
    uint* const bufA = smem;                        // loop: [2][4096] uints (2x16KB fp32 tiles)
    float2* const zuv = (float2*)smem;              // epilogue alias: [128][33] float2 = 33792 B
    float* const als    = (float*)(smem + 8448);
    float* const bls    = (float*)(smem + 8576);
    float* const psr    = (float*)(smem + 8704);
    float* const stat_m = (float*)(smem + 8832);    // [4][32] flat
    float* const stat_s = (float*)(smem + 8960);
    float2* const red   = (float2*)(smem + 9088);   // [8][32] flat
    __shared__ __align__(16) float2 pswl[512];      // 4096 B

    const int t    = threadIdx.x;
    const int lane = t & 63;
    const int w = t >> 6, wr = w >> 1, wc = w & 1;
    const int r0 = blockIdx.x * 128;
    const int hi16 = lane >> 4, lo16 = lane & 15;
    const int r7 = lo16 & 7;

    ((float4*)pswl)[t] = ((const float4*)psw_g)[t];     // 4 KB

    // A DMA addressing (R7-verified): wave w owns rows w*32..+31 (4 insts x 8 rows).
    // LDS linear; source col-group pre-swizzled: agrp = (lane&7) ^ (lane>>3).
    const int arow = (w << 5) | (lane >> 3);
    const int agrp = (lane & 7) ^ ((lane >> 3) & 7);
    const float* xsrc = x + (size_t)(r0 + arow) * 512 + agrp * 4;

    f32x4 acc[4][4];
    #pragma unroll
    for (int i = 0; i < 4; ++i)
        #pragma unroll
        for (int j = 0; j < 4; ++j) acc[i][j] = (f32x4)0.f;
    float paccr[4] = {0.f, 0.f, 0.f, 0.f}, pacct[4] = {0.f, 0.f, 0.f, 0.f};

    // prologue: DMA tile 0
    #pragma unroll
    for (int i = 0; i < 4; ++i)
        gload16(xsrc + (size_t)i * 8 * 512, bufA + (w << 10) + (i << 8));
    __syncthreads();   // tile 0 + pswl visible

    for (int it = 0; it < 16; ++it) {
        const int kt = it << 5;
        const uint* bufAc = bufA + ((it & 1) << 12);

        // ---- issue next tile's DMA (completes by this iter's end barrier) ----
        if (it < 15) {
            uint* dst = bufA + (((it + 1) & 1) << 12) + (w << 10);
            const float* s = xsrc + (size_t)(kt + 32);
            #pragma unroll
            for (int i = 0; i < 4; ++i)
                gload16(s + (size_t)i * 8 * 512, dst + (i << 8));
        }

        // ---- B fragments direct from global (L2-resident; R6-verified) ----
        short8 bhf[4], blf[4];
        #pragma unroll
        for (int nj = 0; nj < 4; ++nj) {
            const int row = (wc << 6) + (nj << 4) + lo16;           // packed W^T row
            const size_t gi = (size_t)row * 64 + (kt >> 3) + hi16;  // uint4 units
            uint4 vh = wht4[gi];
            uint4 vl = wlt4[gi];
            bhf[nj] = *reinterpret_cast<short8*>(&vh);
            blf[nj] = *reinterpret_cast<short8*>(&vl);
        }

        // ---- A fragments from LDS (swizzled read) -> psi fmaf + bf16 split ----
        short8 ahf[4], alf[4];
        if (wc == 0) {
            float4 pw[4];
            #pragma unroll
            for (int c = 0; c < 4; ++c)
                pw[c] = ((const float4*)pswl)[((kt + (hi16 << 3)) >> 1) + c];
            #pragma unroll
            for (int mi = 0; mi < 4; ++mi) {
                const int rowA = (wr << 6) + (mi << 4) + lo16;
                const uint* rp = bufAc + (rowA << 5);
                f32x4 v0 = *(const f32x4*)&rp[(((hi16 << 1)    ) ^ r7) << 2];
                f32x4 v1 = *(const f32x4*)&rp[(((hi16 << 1) | 1) ^ r7) << 2];
                paccr[mi] = fmaf(v0[0], pw[0].x, paccr[mi]); pacct[mi] = fmaf(v0[0], pw[0].y, pacct[mi]);
                paccr[mi] = fmaf(v0[1], pw[0].z, paccr[mi]); pacct[mi] = fmaf(v0[1], pw[0].w, pacct[mi]);
                paccr[mi] = fmaf(v0[2], pw[1].x, paccr[mi]); pacct[mi] = fmaf(v0[2], pw[1].y, pacct[mi]);
                paccr[mi] = fmaf(v0[3], pw[1].z, paccr[mi]); pacct[mi] = fmaf(v0[3], pw[1].w, pacct[mi]);
                paccr[mi] = fmaf(v1[0], pw[2].x, paccr[mi]); pacct[mi] = fmaf(v1[0], pw[2].y, pacct[mi]);
                paccr[mi] = fmaf(v1[1], pw[2].z, paccr[mi]); pacct[mi] = fmaf(v1[1], pw[2].w, pacct[mi]);
                paccr[mi] = fmaf(v1[2], pw[3].x, paccr[mi]); pacct[mi] = fmaf(v1[2], pw[3].y, pacct[mi]);
                paccr[mi] = fmaf(v1[3], pw[3].z, paccr[mi]); pacct[mi] = fmaf(v1[3], pw[3].w, pacct[mi]);
                uint h0, l0, h1, l1, h2, l2, h3, l3;
                split2(v0[0], v0[1], h0, l0);
                split2(v0[2], v0[3], h1, l1);
                split2(v1[0], v1[1], h2, l2);
                split2(v1[2], v1[3], h3, l3);
                uint4 ah = make_uint4(h0, h1, h2, h3), al = make_uint4(l0, l1, l2, l3);
                ahf[mi] = *reinterpret_cast<short8*>(&ah);
                alf[mi] = *reinterpret_cast<short8*>(&al);
            }
        } else {
            #pragma unroll
            for (int mi = 0; mi < 4; ++mi) {
                const int rowA = (wr << 6) + (mi << 4) + lo16;
                const uint* rp = bufAc + (rowA << 5);
                f32x4 v0 = *(const f32x4*)&rp[(((hi16 << 1)    ) ^ r7) << 2];
                f32x4 v1 = *(const f32x4*)&rp[(((hi16 << 1) | 1) ^ r7) << 2];
                uint h0, l0, h1, l1, h2, l2, h3, l3;
                split2(v0[0], v0[1], h0, l0);
                split2(v0[2], v0[3], h1, l1);
                split2(v1[0], v1[1], h2, l2);
                split2(v1[2], v1[3], h3, l3);
                uint4 ah = make_uint4(h0, h1, h2, h3), al = make_uint4(l0, l1, l2, l3);
                ahf[mi] = *reinterpret_cast<short8*>(&ah);
                alf[mi] = *reinterpret_cast<short8*>(&al);
            }
        }

        // ---- MFMA phase (regs only) ----
        #pragma unroll
        for (int nj = 0; nj < 4; ++nj) {
            #pragma unroll
            for (int mi = 0; mi < 4; ++mi) {
                acc[mi][nj] = __builtin_amdgcn_mfma_f32_16x16x32_bf16(ahf[mi], bhf[nj], acc[mi][nj], 0, 0, 0);
                acc[mi][nj] = __builtin_amdgcn_mfma_f32_16x16x32_bf16(ahf[mi], blf[nj], acc[mi][nj], 0, 0, 0);
                acc[mi][nj] = __builtin_amdgcn_mfma_f32_16x16x32_bf16(alf[mi], bhf[nj], acc[mi][nj], 0, 0, 0);
            }
        }
        __syncthreads();   // drains next tile's DMA; all reads of bufAc done
    }

    // ================= epilogue (verbatim R8, passed) =================
    // part 1: psi — reduce per-lane partials across hi16 groups; trans per row
    #pragma unroll
    for (int mi = 0; mi < 4; ++mi) {
        paccr[mi] += __shfl_xor(paccr[mi], 16);
        paccr[mi] += __shfl_xor(paccr[mi], 32);
        pacct[mi] += __shfl_xor(pacct[mi], 16);
        pacct[mi] += __shfl_xor(pacct[mi], 32);
    }
    if (wc == 0 && lane < 16) {
        const float psi_tb = psi_tb_p[0];
        #pragma unroll
        for (int mi = 0; mi < 4; ++mi) {
            const int row = (wr << 6) + (mi << 4) + lane;
            float zr = paccr[mi], zt = pacct[mi];
            float e = fexp2(zr * HLOG2E);
            float tt = ftanh(zt + psi_tb);
            float rev = (1.0f + tt) * 0.5f;
            als[row] = e * fcos1(rev);
            bls[row] = e * fsin1(rev);
            psr[row] = zr;
        }
    }
    __syncthreads();

    // part 2: two passes over nj; stage (u,v) in zuv, reduce with explicit
    // (row,state) indexing.
    const float phi_tb = phi_tb_p[0];
    #pragma unroll
    for (int nj = 0; nj < 2; ++nj) {
        float m = -3.4e38f, s = 0.f;
        #pragma unroll
        for (int mi = 0; mi < 4; ++mi) {
            const int rl = wr * 64 + mi * 16 + hi16 * 4;
            #pragma unroll
            for (int r = 0; r < 4; ++r) {
                float zr = acc[mi][nj][r];
                float zt = acc[mi][nj + 2][r];
                float eh = fexp2(zr * HLOG2E);
                float tt = ftanh(zt + phi_tb);
                float rev = -(1.0f + PI_F * tt) * 0.5f;
                rev = rev - floorf(rev);
                float u = eh * fcos1(rev), v = eh * fsin1(rev);
                zuv[(rl + r) * 33 + wc * 16 + lo16] = make_float2(u, v);
                float nm = fmaxf(m, zr);
                s = s * fexp2((m - nm) * LOG2E) + fexp2((zr - nm) * LOG2E);
                m = nm;
            }
        }
        #pragma unroll
        for (int off = 16; off <= 32; off <<= 1) {
            float m2 = __shfl_xor(m, off);
            float s2 = __shfl_xor(s, off);
            onl(m, s, m2, s2);
        }
        if (lane < 16) { stat_m[w * 32 + nj * 16 + lo16] = m; stat_s[w * 32 + nj * 16 + lo16] = s; }
        __syncthreads();

        {
            const int slot = t & 31, q = t >> 5;
            float re = 0.f, im = 0.f;
            #pragma unroll
            for (int i = 0; i < 16; ++i) {
                const int row = q + 8 * i;
                float2 uvv = zuv[row * 33 + slot];
                float a = als[row], b2 = bls[row];
                re = fmaf(a, uvv.x, fmaf(b2, uvv.y, re));   // cos(A-B)
                im = fmaf(b2, uvv.x, fmaf(-a, uvv.y, im));  // sin(A-B)
            }
            red[q * 32 + slot] = make_float2(re, im);
        }
        __syncthreads();
        if (t < 32) {
            float re = 0.f, im = 0.f;
            #pragma unroll
            for (int q = 0; q < 8; ++q) { re += red[q * 32 + t].x; im += red[q * 32 + t].y; }
            const int state = ((t >> 4) << 5) | (nj << 4) | (t & 15);
            pri[(size_t)blockIdx.x * 64 + state] = make_float2(re, im);
        }
        __syncthreads();
    }

    // part 3: combine per-wave stats -> per-block partials
    if (t < 64) {
        const int wcn = t >> 5, nloc = t & 31;
        float M = stat_m[wcn * 32 + nloc], S = stat_s[wcn * 32 + nloc];
        onl(M, S, stat_m[(wcn + 2) * 32 + nloc], stat_s[(wcn + 2) * 32 + nloc]);
        pmphi[(size_t)blockIdx.x * 64 + t] = M;
        psphi[(size_t)blockIdx.x * 64 + t] = S;
    } else if (t < 128) {
        const int i = t - 64;
        float a = psr[i], bb = psr[i + 64];
        float M = fmaxf(a, bb);
        float S = fexp2((a - M) * LOG2E) + fexp2((bb - M) * LOG2E);
        #pragma unroll
        for (int off = 1; off <= 32; off <<= 1) {
            float m2 = __shfl_xor(M, off);
            float s2 = __shfl_xor(S, off);
            onl(M, S, m2, s2);
        }
        if (i == 0) { pmpsi[blockIdx.x] = M; pspsi[blockIdx.x] = S; }
    }
}

// K5: per batch: combine 32 block partials -> scales -> collapse -> out GEMM
__global__ __launch_bounds__(512) void k5_out(
        const float2* __restrict__ pri,
        const float* __restrict__ pmphi, const float* __restrict__ psphi,
        const float* __restrict__ pmpsi, const float* __restrict__ pspsi,
        const float* __restrict__ Smat, const float* __restrict__ sb_p,
        float* __restrict__ out) {
    const int b = blockIdx.x, t = threadIdx.x;
    __shared__ float cls[64];
    __shared__ float spsi_s;
    float sph = 0.f, re = 0.f, im = 0.f;
    if (t < 64) {
        float M = -3.4e38f, S = 0.f;
        for (int ch = 0; ch < 32; ++ch)
            onl(M, S, pmphi[(size_t)(b * 32 + ch) * 64 + t], psphi[(size_t)(b * 32 + ch) * 64 + t]);
        sph = fexp2(-M * HLOG2E) / sqrtf(S);
        for (int ch = 0; ch < 32; ++ch) {
            float2 p = pri[(size_t)(b * 32 + ch) * 64 + t];
            re += p.x; im += p.y;
        }
    } else if (t == 64) {
        float M = -3.4e38f, S = 0.f;
        for (int ch = 0; ch < 32; ++ch)
            onl(M, S, pmpsi[b * 32 + ch], pspsi[b * 32 + ch]);
        spsi_s = fexp2(-M * HLOG2E) / sqrtf(S);
    }
    __syncthreads();
    if (t < 64) {
        float sc = spsi_s * sph;
        cls[t] = sc * sc * (re * re + im * im);
    }
    __syncthreads();
    float acc = sb_p[0];
    #pragma unroll 8
    for (int n = 0; n < 64; ++n) acc = fmaf(cls[n], Smat[n * UNITS + t], acc);
    out[(size_t)b * UNITS + t] = acc;
}

extern "C" void kernel_launch(void* const* d_in, const int* in_sizes, int n_in,
                              void* d_out, int out_size, void* d_ws, size_t ws_size,
                              hipStream_t stream) {
    const float* x      = (const float*)d_in[0];
    const float* psi_r  = (const float*)d_in[1];
    const float* psi_t  = (const float*)d_in[2];
    const float* psi_tb = (const float*)d_in[3];
    const float* phi_r  = (const float*)d_in[4];
    const float* phi_t  = (const float*)d_in[5];
    const float* phi_tb = (const float*)d_in[6];
    const float* Smat   = (const float*)d_in[7];
    const float* sb     = (const float*)d_in[8];
    float* out = (float*)d_out;

    char* ws = (char*)d_ws;
    ushort* wht  = (ushort*)(ws + OFF_WHT);
    ushort* wlt  = (ushort*)(ws + OFF_WLT);
    float2* psw  = (float2*)(ws + OFF_PSW);
    float2* pri  = (float2*)(ws + OFF_PRI);
    float* pmphi = (float*)(ws + OFF_PMPHI);
    float* psphi = (float*)(ws + OFF_PSPHI);
    float* pmpsi = (float*)(ws + OFF_PMPSI);
    float* pspsi = (float*)(ws + OFF_PSPSI);

    k0_pack<<<512, 64, 0, stream>>>(psi_r, psi_t, phi_r, phi_t, wht, wlt, psw);
    k1_gemm<<<ROWS / 128, 256, 0, stream>>>(x, (const uint4*)wht, (const uint4*)wlt, psw,
                                            psi_tb, phi_tb, pri, pmphi, psphi, pmpsi, pspsi);
    k5_out<<<B_, 512, 0, stream>>>(pri, pmphi, psphi, pmpsi, pspsi, Smat, sb, out);
}